// Round 9
// baseline (1972.899 us; speedup 1.0000x reference)
//
#include <hip/hip_runtime.h>
#include <hip/hip_bf16.h>

// Problem constants
#define Vv 50000
#define Ee 300
#define HIDc 256
#define Tt 9
#define Bb 32
#define Ss 512
#define Hh 128
#define Mtok (Bb*Ss)      // 16384

__device__ __forceinline__ float sigm(float x) {
    return 1.0f / (1.0f + __expf(-x));
}
__device__ __forceinline__ float tanhx(float x) {
    // tanh(x) = 1 - 2/(exp(2x)+1); safe at extremes (exp->inf gives 1, exp->0 gives -1)
    return 1.0f - 2.0f / (__expf(2.0f * x) + 1.0f);
}

// ---------------- embedding gather: e[token][0..299] = emb[x[token]] ----------------
__global__ __launch_bounds__(256) void embed_gather(const float* __restrict__ emb,
                                                    const int* __restrict__ x,
                                                    float* __restrict__ e) {
    int idx = blockIdx.x * 256 + threadIdx.x;      // token*75 + q, 75 float4 per row
    if (idx >= Mtok * 75) return;
    int token = idx / 75, q = idx % 75;
    ((float4*)e)[idx] = ((const float4*)emb)[(size_t)x[token] * 75 + q];
}

// ---------------- xg = A @ W^T + bih + bhh, for both directions (blockIdx.z) -------
// A: [Mtok][K] row-major; W: [512][K] row-major; out: [2][Mtok][512]
template<int K>
__global__ __launch_bounds__(256) void xg_gemm(const float* __restrict__ A,
                                               const float* __restrict__ Wf, const float* __restrict__ Wb,
                                               const float* __restrict__ bihf, const float* __restrict__ bhhf,
                                               const float* __restrict__ bihb, const float* __restrict__ bhhb,
                                               float* __restrict__ out) {
    constexpr int NKT = (K + 15) / 16;
    const int dir = blockIdx.z;
    const float* W   = dir ? Wb   : Wf;
    const float* bih = dir ? bihb : bihf;
    const float* bhh = dir ? bhhb : bhhf;
    const int m0 = blockIdx.y * 128;
    const int n0 = blockIdx.x * 64;

    __shared__ float As[16][128];   // k-major
    __shared__ float Bs[16][64];

    const int tid = threadIdx.x;
    const int tx = tid & 15, ty = tid >> 4;     // n-group (4), m-group (8)
    const int ma = tid & 127, qa = tid >> 7;    // A staging: row, k-half (8 each)
    const int nw = tid & 63,  qw = tid >> 6;    // W staging: row, k-quarter (4 each)

    float acc[8][4] = {};

    for (int kt = 0; kt < NKT; ++kt) {
        const int k0 = kt * 16;
        // stage A tile (transposed into k-major LDS)
        #pragma unroll
        for (int r = 0; r < 2; ++r) {
            int kl = qa * 8 + r * 4;
            float4 v = make_float4(0.f, 0.f, 0.f, 0.f);
            if (k0 + kl < K)
                v = *(const float4*)(A + (size_t)(m0 + ma) * K + k0 + kl);
            As[kl + 0][ma] = v.x; As[kl + 1][ma] = v.y;
            As[kl + 2][ma] = v.z; As[kl + 3][ma] = v.w;
        }
        // stage W tile
        {
            int kl = qw * 4;
            float4 v = make_float4(0.f, 0.f, 0.f, 0.f);
            if (k0 + kl < K)
                v = *(const float4*)(W + (size_t)(n0 + nw) * K + k0 + kl);
            Bs[kl + 0][nw] = v.x; Bs[kl + 1][nw] = v.y;
            Bs[kl + 2][nw] = v.z; Bs[kl + 3][nw] = v.w;
        }
        __syncthreads();
        #pragma unroll
        for (int k = 0; k < 16; ++k) {
            float4 a0 = *(const float4*)&As[k][ty * 8];
            float4 a1 = *(const float4*)&As[k][ty * 8 + 4];
            float4 b  = *(const float4*)&Bs[k][tx * 4];
            float av[8] = {a0.x, a0.y, a0.z, a0.w, a1.x, a1.y, a1.z, a1.w};
            float bv[4] = {b.x, b.y, b.z, b.w};
            #pragma unroll
            for (int i = 0; i < 8; ++i)
                #pragma unroll
                for (int j = 0; j < 4; ++j)
                    acc[i][j] += av[i] * bv[j];
        }
        __syncthreads();
    }
    // epilogue: + bih + bhh, store
    #pragma unroll
    for (int j = 0; j < 4; ++j) {
        int n = n0 + tx * 4 + j;
        float bsum = bih[n] + bhh[n];
        #pragma unroll
        for (int i = 0; i < 8; ++i) acc[i][j] += bsum;
    }
    #pragma unroll
    for (int i = 0; i < 8; ++i) {
        int m = m0 + ty * 8 + i;
        *(float4*)(out + ((size_t)dir * Mtok + m) * 512 + n0 + tx * 4) =
            make_float4(acc[i][0], acc[i][1], acc[i][2], acc[i][3]);
    }
}

// ---------------- LSTM recurrent scan: one WG per (batch, direction) --------------
// 1024 threads: thread = (gate row o = tid>>1, k-half = tid&1).
// Each thread holds 64 whh weights in 16 NAMED float4s wr0..wr15 (SROA-guaranteed
// VGPR residency — Round-2 profile showed float w[128] was demoted to re-loads,
// VGPR_Count=80, causing ~14.8 TB/s of L2 traffic).
// xg: [2][Mtok][512]  (dir-major); whh: [512][128]; hout: [Mtok][256]
#define W16(F) F(0) F(1) F(2) F(3) F(4) F(5) F(6) F(7) F(8) F(9) F(10) F(11) F(12) F(13) F(14) F(15)
__global__ __launch_bounds__(1024, 1) void lstm_scan(const float* __restrict__ xg,
                                                     const float* __restrict__ whhf,
                                                     const float* __restrict__ whhb,
                                                     float* __restrict__ hout) {
    const int b   = blockIdx.x & 31;
    const int dir = blockIdx.x >> 5;
    const int tid = threadIdx.x;
    const int o    = tid >> 1;        // gate row 0..511
    const int half = tid & 1;         // k-half (0: h[0..63], 1: h[64..127])
    const float* whh = dir ? whhb : whhf;

    const float4* wbase = (const float4*)(whh + (size_t)o * 128 + half * 64);
#define WLOAD(i) const float4 wr##i = wbase[i];
    W16(WLOAD)
#undef WLOAD

    __shared__ float h_lds[128];
    __shared__ float g_lds[512];
    float c = 0.f;
    if (tid < 128) h_lds[tid] = 0.f;
    __syncthreads();

    const float* xgb = xg + ((size_t)dir * Mtok + (size_t)b * Ss) * 512;
    int t = dir ? (Ss - 1) : 0;
    const int dt = dir ? -1 : 1;
    float xv = xgb[(size_t)t * 512 + o];   // prefetch step 0
    const int cls = o >> 7;                // 0:i 1:f 2:g 3:o (wave-uniform)

    for (int step = 0; step < Ss; ++step) {
        const float4* h4 = (const float4*)h_lds + half * 16;
        float g0 = 0.f, g1 = 0.f, g2 = 0.f, g3 = 0.f;
#define WDOT(i) { float4 hv = h4[i]; g0 += hv.x * wr##i.x; g1 += hv.y * wr##i.y; \
                  g2 += hv.z * wr##i.z; g3 += hv.w * wr##i.w; }
        W16(WDOT)
#undef WDOT
        float g = (g0 + g1) + (g2 + g3);
        g += __shfl_xor(g, 1);             // combine the two k-halves
        g += xv;
        int tn = t + dt;
        if (step + 1 < Ss) xv = xgb[(size_t)tn * 512 + o];   // prefetch next step
        // gate nonlinearity in the wide phase (wave-uniform branch)
        float act = (cls == 2) ? tanhx(g) : sigm(g);
        if (half == 0) g_lds[o] = act;
        __syncthreads();
        if (tid < 128) {
            c = g_lds[tid + 128] * c + g_lds[tid] * g_lds[tid + 256];
            float h = g_lds[tid + 384] * tanhx(c);
            h_lds[tid] = h;
            hout[((size_t)b * Ss + t) * 256 + dir * 128 + tid] = h;
        }
        __syncthreads();
        t = tn;
    }
}

// ---------------- emissions = h1 @ wproj^T + bproj --------------------------------
__global__ __launch_bounds__(256) void emis_kernel(const float* __restrict__ h1,
                                                   const float* __restrict__ wproj,
                                                   const float* __restrict__ bproj,
                                                   float* __restrict__ em) {
    int idx = blockIdx.x * 256 + threadIdx.x;   // token*9 + tag
    if (idx >= Mtok * Tt) return;
    int token = idx / Tt, tg = idx % Tt;
    const float4* hp = (const float4*)(h1 + (size_t)token * 256);
    const float4* wp = (const float4*)(wproj + (size_t)tg * 256);
    float acc = bproj[tg];
    #pragma unroll 8
    for (int q = 0; q < 64; ++q) {
        float4 a = hp[q], b = wp[q];
        acc += a.x * b.x + a.y * b.y + a.z * b.z + a.w * b.w;
    }
    em[idx] = acc;
}

// ---------------- CRF numerator per batch -----------------------------------------
// NOTE: mask is a jnp bool array -> staged by harness as int32, NOT uint8.
__global__ __launch_bounds__(256) void crf_num(const float* __restrict__ em,
                                               const int* __restrict__ tags,
                                               const int* __restrict__ mask,
                                               const float* __restrict__ start_t,
                                               const float* __restrict__ end_t,
                                               const float* __restrict__ trans,
                                               float* __restrict__ num) {
    const int b = blockIdx.x;
    const int tid = threadIdx.x;
    __shared__ float sp[256];
    __shared__ int   sc[256];
    float p = 0.f; int cnt = 0;
    for (int t = 1 + tid; t < Ss; t += 256) {
        int mk = mask[b * Ss + t] != 0;
        int tg = tags[b * Ss + t], tp = tags[b * Ss + t - 1];
        if (mk) p += trans[tp * Tt + tg] + em[((size_t)b * Ss + t) * Tt + tg];
        cnt += mk;
    }
    if (tid == 0) cnt += (mask[b * Ss] != 0);
    sp[tid] = p; sc[tid] = cnt;
    __syncthreads();
    for (int s = 128; s > 0; s >>= 1) {
        if (tid < s) { sp[tid] += sp[tid + s]; sc[tid] += sc[tid + s]; }
        __syncthreads();
    }
    if (tid == 0) {
        int t0 = tags[b * Ss];
        float v = start_t[t0] + em[(size_t)b * Ss * Tt + t0] + sp[0];
        int sl = sc[0];
        v += end_t[tags[b * Ss + sl - 1]];
        num[b] = v;
    }
}

// ---------------- CRF alpha scan + final NLL --------------------------------------
__global__ __launch_bounds__(512) void crf_alpha(const float* __restrict__ em,
                                                 const int* __restrict__ mask,
                                                 const float* __restrict__ start_t,
                                                 const float* __restrict__ end_t,
                                                 const float* __restrict__ trans,
                                                 const float* __restrict__ num,
                                                 float* __restrict__ out) {
    __shared__ float al[2][Bb][12];   // padded 9->12
    __shared__ float tr[Tt * Tt];
    __shared__ float red[Bb];
    const int tid = threadIdx.x;
    if (tid < Tt * Tt) tr[tid] = trans[tid];
    const int b = tid / Tt, j = tid % Tt;
    const bool act = tid < Bb * Tt;
    if (act) al[0][b][j] = start_t[j] + em[(size_t)b * Ss * Tt + j];
    __syncthreads();

    int cur = 0;
    float emn = act ? em[((size_t)b * Ss + 1) * Tt + j] : 0.f;
    for (int t = 1; t < Ss; ++t) {
        float nv = 0.f;
        if (act) {
            float v[Tt];
            float mx = -1e30f;
            #pragma unroll
            for (int i = 0; i < Tt; ++i) {
                v[i] = al[cur][b][i] + tr[i * Tt + j];
                mx = fmaxf(mx, v[i]);
            }
            float s = 0.f;
            #pragma unroll
            for (int i = 0; i < Tt; ++i) s += __expf(v[i] - mx);
            nv = mx + __logf(s) + emn;
            int mk = mask[b * Ss + t] != 0;
            if (t + 1 < Ss) emn = em[((size_t)b * Ss + t + 1) * Tt + j];
            if (!mk) nv = al[cur][b][j];
            al[cur ^ 1][b][j] = nv;
        }
        __syncthreads();
        cur ^= 1;
    }
    if (tid < Bb) {
        float mx = -1e30f;
        float v[Tt];
        #pragma unroll
        for (int jj = 0; jj < Tt; ++jj) {
            v[jj] = al[cur][tid][jj] + end_t[jj];
            mx = fmaxf(mx, v[jj]);
        }
        float s = 0.f;
        #pragma unroll
        for (int jj = 0; jj < Tt; ++jj) s += __expf(v[jj] - mx);
        float denom = mx + __logf(s);
        red[tid] = num[tid] - denom;
    }
    __syncthreads();
    if (tid == 0) {
        float s = 0.f;
        #pragma unroll
        for (int bb = 0; bb < Bb; ++bb) s += red[bb];
        out[0] = -(s / (float)Bb);
    }
}

// ---------------- launch -----------------------------------------------------------
extern "C" void kernel_launch(void* const* d_in, const int* in_sizes, int n_in,
                              void* d_out, int out_size, void* d_ws, size_t ws_size,
                              hipStream_t stream) {
    const float* emb   = (const float*)d_in[0];
    const float* wih0f = (const float*)d_in[1];  const float* whh0f = (const float*)d_in[2];
    const float* bih0f = (const float*)d_in[3];  const float* bhh0f = (const float*)d_in[4];
    const float* wih0b = (const float*)d_in[5];  const float* whh0b = (const float*)d_in[6];
    const float* bih0b = (const float*)d_in[7];  const float* bhh0b = (const float*)d_in[8];
    const float* wih1f = (const float*)d_in[9];  const float* whh1f = (const float*)d_in[10];
    const float* bih1f = (const float*)d_in[11]; const float* bhh1f = (const float*)d_in[12];
    const float* wih1b = (const float*)d_in[13]; const float* whh1b = (const float*)d_in[14];
    const float* bih1b = (const float*)d_in[15]; const float* bhh1b = (const float*)d_in[16];
    const float* wproj = (const float*)d_in[17]; const float* bproj = (const float*)d_in[18];
    const float* start_t = (const float*)d_in[19];
    const float* end_t   = (const float*)d_in[20];
    const float* trans_t = (const float*)d_in[21];
    const int* x    = (const int*)d_in[22];
    const int* tags = (const int*)d_in[23];
    const int* mask = (const int*)d_in[24];

    float* ws   = (float*)d_ws;
    float* e_buf = ws;                                  // 16384*300      (reused as h1)
    float* xg    = e_buf + (size_t)Mtok * Ee;           // 2*16384*512
    float* h0    = xg + (size_t)2 * Mtok * 512;         // 16384*256
    float* em    = h0 + (size_t)Mtok * 256;             // 16384*9
    float* num   = em + (size_t)Mtok * Tt;              // 32
    float* h1    = e_buf;                               // alias: e dead after xg layer0
    float* outp  = (float*)d_out;

    embed_gather<<<(Mtok * 75 + 255) / 256, 256, 0, stream>>>(emb, x, e_buf);
    xg_gemm<Ee><<<dim3(8, 128, 2), 256, 0, stream>>>(e_buf, wih0f, wih0b,
                                                     bih0f, bhh0f, bih0b, bhh0b, xg);
    lstm_scan<<<64, 1024, 0, stream>>>(xg, whh0f, whh0b, h0);
    xg_gemm<HIDc><<<dim3(8, 128, 2), 256, 0, stream>>>(h0, wih1f, wih1b,
                                                       bih1f, bhh1f, bih1b, bhh1b, xg);
    lstm_scan<<<64, 1024, 0, stream>>>(xg, whh1f, whh1b, h1);
    emis_kernel<<<(Mtok * Tt + 255) / 256, 256, 0, stream>>>(h1, wproj, bproj, em);
    crf_num<<<32, 256, 0, stream>>>(em, tags, mask, start_t, end_t, trans_t, num);
    crf_alpha<<<1, 512, 0, stream>>>(em, mask, start_t, end_t, trans_t, num, outp);
}

// Round 10
// 1467.776 us; speedup vs baseline: 1.3441x; 1.3441x over previous
//
#include <hip/hip_runtime.h>
#include <hip/hip_bf16.h>

// Problem constants
#define Vv 50000
#define Ee 300
#define HIDc 256
#define Tt 9
#define Bb 32
#define Ss 512
#define Hh 128
#define Mtok (Bb*Ss)      // 16384

// Set to 1 if __builtin_amdgcn_fdot2 fails to compile for gfx950.
#define LSTM_NODOT2 0

__device__ __forceinline__ float sigm(float x) {
    return 1.0f / (1.0f + __expf(-x));
}
__device__ __forceinline__ float tanhx(float x) {
    // tanh(x) = 1 - 2/(exp(2x)+1); safe at extremes
    return 1.0f - 2.0f / (__expf(2.0f * x) + 1.0f);
}

typedef _Float16 half2v __attribute__((ext_vector_type(2)));

__device__ __forceinline__ unsigned short f2h_bits(float x) {
    union { _Float16 h; unsigned short s; } u;
    u.h = (_Float16)x;            // v_cvt_f16_f32, RNE
    return u.s;
}

__device__ __forceinline__ float dot2(unsigned int w, unsigned int h, float acc) {
    union { unsigned int u; half2v v; } a, b;
    a.u = w; b.u = h;
#if LSTM_NODOT2
    return acc + (float)a.v.x * (float)b.v.x + (float)a.v.y * (float)b.v.y;
#else
    return __builtin_amdgcn_fdot2(a.v, b.v, acc, false);
#endif
}

// ---------------- embedding gather: e[token][0..299] = emb[x[token]] ----------------
__global__ __launch_bounds__(256) void embed_gather(const float* __restrict__ emb,
                                                    const int* __restrict__ x,
                                                    float* __restrict__ e) {
    int idx = blockIdx.x * 256 + threadIdx.x;      // token*75 + q, 75 float4 per row
    if (idx >= Mtok * 75) return;
    int token = idx / 75, q = idx % 75;
    ((float4*)e)[idx] = ((const float4*)emb)[(size_t)x[token] * 75 + q];
}

// ---------------- xg = A @ W^T + bih + bhh, for both directions (blockIdx.z) -------
// A: [Mtok][K] row-major; W: [512][K] row-major; out: [2][Mtok][512]
template<int K>
__global__ __launch_bounds__(256) void xg_gemm(const float* __restrict__ A,
                                               const float* __restrict__ Wf, const float* __restrict__ Wb,
                                               const float* __restrict__ bihf, const float* __restrict__ bhhf,
                                               const float* __restrict__ bihb, const float* __restrict__ bhhb,
                                               float* __restrict__ out) {
    constexpr int NKT = (K + 15) / 16;
    const int dir = blockIdx.z;
    const float* W   = dir ? Wb   : Wf;
    const float* bih = dir ? bihb : bihf;
    const float* bhh = dir ? bhhb : bhhf;
    const int m0 = blockIdx.y * 128;
    const int n0 = blockIdx.x * 64;

    __shared__ float As[16][128];   // k-major
    __shared__ float Bs[16][64];

    const int tid = threadIdx.x;
    const int tx = tid & 15, ty = tid >> 4;     // n-group (4), m-group (8)
    const int ma = tid & 127, qa = tid >> 7;    // A staging: row, k-half (8 each)
    const int nw = tid & 63,  qw = tid >> 6;    // W staging: row, k-quarter (4 each)

    float acc[8][4] = {};

    for (int kt = 0; kt < NKT; ++kt) {
        const int k0 = kt * 16;
        #pragma unroll
        for (int r = 0; r < 2; ++r) {
            int kl = qa * 8 + r * 4;
            float4 v = make_float4(0.f, 0.f, 0.f, 0.f);
            if (k0 + kl < K)
                v = *(const float4*)(A + (size_t)(m0 + ma) * K + k0 + kl);
            As[kl + 0][ma] = v.x; As[kl + 1][ma] = v.y;
            As[kl + 2][ma] = v.z; As[kl + 3][ma] = v.w;
        }
        {
            int kl = qw * 4;
            float4 v = make_float4(0.f, 0.f, 0.f, 0.f);
            if (k0 + kl < K)
                v = *(const float4*)(W + (size_t)(n0 + nw) * K + k0 + kl);
            Bs[kl + 0][nw] = v.x; Bs[kl + 1][nw] = v.y;
            Bs[kl + 2][nw] = v.z; Bs[kl + 3][nw] = v.w;
        }
        __syncthreads();
        #pragma unroll
        for (int k = 0; k < 16; ++k) {
            float4 a0 = *(const float4*)&As[k][ty * 8];
            float4 a1 = *(const float4*)&As[k][ty * 8 + 4];
            float4 b  = *(const float4*)&Bs[k][tx * 4];
            float av[8] = {a0.x, a0.y, a0.z, a0.w, a1.x, a1.y, a1.z, a1.w};
            float bv[4] = {b.x, b.y, b.z, b.w};
            #pragma unroll
            for (int i = 0; i < 8; ++i)
                #pragma unroll
                for (int j = 0; j < 4; ++j)
                    acc[i][j] += av[i] * bv[j];
        }
        __syncthreads();
    }
    #pragma unroll
    for (int j = 0; j < 4; ++j) {
        int n = n0 + tx * 4 + j;
        float bsum = bih[n] + bhh[n];
        #pragma unroll
        for (int i = 0; i < 8; ++i) acc[i][j] += bsum;
    }
    #pragma unroll
    for (int i = 0; i < 8; ++i) {
        int m = m0 + ty * 8 + i;
        *(float4*)(out + ((size_t)dir * Mtok + m) * 512 + n0 + tx * 4) =
            make_float4(acc[i][0], acc[i][1], acc[i][2], acc[i][3]);
    }
}

// ---------------- LSTM recurrent scan: one WG per (batch, direction) --------------
// Rounds 2 & 9 proved the compiler will NOT keep the 256 KB whh resident in VGPRs
// (VGPR_Count 80/48; weights streamed through L1 at its ~200 GB/s/CU ceiling).
// New structure: weights quantized to f16 and staged ONCE into LDS (128 KB, the
// only residency the compiler can't undo). 512 threads, one per gate row.
// LDS layout wlds16[kc][o][8] (kc = k/8): thread o's 8 f16 weights for k-chunk kc
// are one aligned 16B b128 read; start banks 4*o mod 32 -> equal bank loading.
// h kept packed f16x2 in hp[] (broadcast reads, conflict-free).
// Dot product: v_dot2_f32_f16 (2 MAC/instr, fp32 accumulate), 4 indep chains.
// xg: [2][Mtok][512]; whh: [512][128]; hout: [Mtok][256]
__global__ __launch_bounds__(512, 1) void lstm_scan(const float* __restrict__ xg,
                                                    const float* __restrict__ whhf,
                                                    const float* __restrict__ whhb,
                                                    float* __restrict__ hout) {
    const int b   = blockIdx.x & 31;
    const int dir = blockIdx.x >> 5;
    const int tid = threadIdx.x;
    const int o   = tid;              // gate row 0..511
    const float* whh = dir ? whhb : whhf;

    __shared__ unsigned short wlds16[16 * 512 * 8];   // 128 KB f16 weights
    __shared__ unsigned int   hp[64];                 // 128 h as f16x2
    __shared__ float          g_lds[512];

    // ---- stage whh -> f16 LDS (one-time, coalesced global reads) ----
    for (int e = tid; e < 512 * 128; e += 512) {
        int ro = e >> 7, k = e & 127;
        wlds16[((k >> 3) * 512 + ro) * 8 + (k & 7)] = f2h_bits(whh[e]);
    }
    if (tid < 64) hp[tid] = 0u;       // h = 0
    float c = 0.f;
    __syncthreads();

    const float* xgb = xg + ((size_t)dir * Mtok + (size_t)b * Ss) * 512;
    int t = dir ? (Ss - 1) : 0;
    const int dt = dir ? -1 : 1;
    float xv = xgb[(size_t)t * 512 + o];   // prefetch step 0
    const int cls = o >> 7;                // 0:i 1:f 2:g 3:o (wave-uniform)

    for (int step = 0; step < Ss; ++step) {
        float a0 = 0.f, a1 = 0.f, a2 = 0.f, a3 = 0.f;
        #pragma unroll
        for (int kc = 0; kc < 16; ++kc) {
            uint4 wv = *(const uint4*)(wlds16 + ((kc * 512 + o) * 8));
            uint4 hv = *(const uint4*)((const unsigned short*)hp + kc * 8);
            a0 = dot2(wv.x, hv.x, a0);
            a1 = dot2(wv.y, hv.y, a1);
            a2 = dot2(wv.z, hv.z, a2);
            a3 = dot2(wv.w, hv.w, a3);
        }
        float g = ((a0 + a1) + (a2 + a3)) + xv;
        int tn = t + dt;
        if (step + 1 < Ss) xv = xgb[(size_t)tn * 512 + o];   // prefetch next step
        // gate nonlinearity in the wide phase (wave-uniform branch)
        g_lds[o] = (cls == 2) ? tanhx(g) : sigm(g);
        __syncthreads();
        if (tid < 128) {
            c = g_lds[tid + 128] * c + g_lds[tid] * g_lds[tid + 256];
            float h = g_lds[tid + 384] * tanhx(c);
            hout[((size_t)b * Ss + t) * 256 + dir * 128 + tid] = h;   // fp32 out
            ((unsigned short*)hp)[tid] = f2h_bits(h);                 // f16 recurrent
        }
        __syncthreads();
        t = tn;
    }
}

// ---------------- emissions = h1 @ wproj^T + bproj --------------------------------
__global__ __launch_bounds__(256) void emis_kernel(const float* __restrict__ h1,
                                                   const float* __restrict__ wproj,
                                                   const float* __restrict__ bproj,
                                                   float* __restrict__ em) {
    int idx = blockIdx.x * 256 + threadIdx.x;   // token*9 + tag
    if (idx >= Mtok * Tt) return;
    int token = idx / Tt, tg = idx % Tt;
    const float4* hp = (const float4*)(h1 + (size_t)token * 256);
    const float4* wp = (const float4*)(wproj + (size_t)tg * 256);
    float acc = bproj[tg];
    #pragma unroll 8
    for (int q = 0; q < 64; ++q) {
        float4 a = hp[q], b = wp[q];
        acc += a.x * b.x + a.y * b.y + a.z * b.z + a.w * b.w;
    }
    em[idx] = acc;
}

// ---------------- CRF numerator per batch -----------------------------------------
// NOTE: mask is a jnp bool array -> staged by harness as int32, NOT uint8.
__global__ __launch_bounds__(256) void crf_num(const float* __restrict__ em,
                                               const int* __restrict__ tags,
                                               const int* __restrict__ mask,
                                               const float* __restrict__ start_t,
                                               const float* __restrict__ end_t,
                                               const float* __restrict__ trans,
                                               float* __restrict__ num) {
    const int b = blockIdx.x;
    const int tid = threadIdx.x;
    __shared__ float sp[256];
    __shared__ int   sc[256];
    float p = 0.f; int cnt = 0;
    for (int t = 1 + tid; t < Ss; t += 256) {
        int mk = mask[b * Ss + t] != 0;
        int tg = tags[b * Ss + t], tp = tags[b * Ss + t - 1];
        if (mk) p += trans[tp * Tt + tg] + em[((size_t)b * Ss + t) * Tt + tg];
        cnt += mk;
    }
    if (tid == 0) cnt += (mask[b * Ss] != 0);
    sp[tid] = p; sc[tid] = cnt;
    __syncthreads();
    for (int s = 128; s > 0; s >>= 1) {
        if (tid < s) { sp[tid] += sp[tid + s]; sc[tid] += sc[tid + s]; }
        __syncthreads();
    }
    if (tid == 0) {
        int t0 = tags[b * Ss];
        float v = start_t[t0] + em[(size_t)b * Ss * Tt + t0] + sp[0];
        int sl = sc[0];
        v += end_t[tags[b * Ss + sl - 1]];
        num[b] = v;
    }
}

// ---------------- CRF alpha scan + final NLL --------------------------------------
__global__ __launch_bounds__(512) void crf_alpha(const float* __restrict__ em,
                                                 const int* __restrict__ mask,
                                                 const float* __restrict__ start_t,
                                                 const float* __restrict__ end_t,
                                                 const float* __restrict__ trans,
                                                 const float* __restrict__ num,
                                                 float* __restrict__ out) {
    __shared__ float al[2][Bb][12];   // padded 9->12
    __shared__ float tr[Tt * Tt];
    __shared__ float red[Bb];
    const int tid = threadIdx.x;
    if (tid < Tt * Tt) tr[tid] = trans[tid];
    const int b = tid / Tt, j = tid % Tt;
    const bool act = tid < Bb * Tt;
    if (act) al[0][b][j] = start_t[j] + em[(size_t)b * Ss * Tt + j];
    __syncthreads();

    int cur = 0;
    float emn = act ? em[((size_t)b * Ss + 1) * Tt + j] : 0.f;
    for (int t = 1; t < Ss; ++t) {
        float nv = 0.f;
        if (act) {
            float v[Tt];
            float mx = -1e30f;
            #pragma unroll
            for (int i = 0; i < Tt; ++i) {
                v[i] = al[cur][b][i] + tr[i * Tt + j];
                mx = fmaxf(mx, v[i]);
            }
            float s = 0.f;
            #pragma unroll
            for (int i = 0; i < Tt; ++i) s += __expf(v[i] - mx);
            nv = mx + __logf(s) + emn;
            int mk = mask[b * Ss + t] != 0;
            if (t + 1 < Ss) emn = em[((size_t)b * Ss + t + 1) * Tt + j];
            if (!mk) nv = al[cur][b][j];
            al[cur ^ 1][b][j] = nv;
        }
        __syncthreads();
        cur ^= 1;
    }
    if (tid < Bb) {
        float mx = -1e30f;
        float v[Tt];
        #pragma unroll
        for (int jj = 0; jj < Tt; ++jj) {
            v[jj] = al[cur][tid][jj] + end_t[jj];
            mx = fmaxf(mx, v[jj]);
        }
        float s = 0.f;
        #pragma unroll
        for (int jj = 0; jj < Tt; ++jj) s += __expf(v[jj] - mx);
        float denom = mx + __logf(s);
        red[tid] = num[tid] - denom;
    }
    __syncthreads();
    if (tid == 0) {
        float s = 0.f;
        #pragma unroll
        for (int bb = 0; bb < Bb; ++bb) s += red[bb];
        out[0] = -(s / (float)Bb);
    }
}

// ---------------- launch -----------------------------------------------------------
extern "C" void kernel_launch(void* const* d_in, const int* in_sizes, int n_in,
                              void* d_out, int out_size, void* d_ws, size_t ws_size,
                              hipStream_t stream) {
    const float* emb   = (const float*)d_in[0];
    const float* wih0f = (const float*)d_in[1];  const float* whh0f = (const float*)d_in[2];
    const float* bih0f = (const float*)d_in[3];  const float* bhh0f = (const float*)d_in[4];
    const float* wih0b = (const float*)d_in[5];  const float* whh0b = (const float*)d_in[6];
    const float* bih0b = (const float*)d_in[7];  const float* bhh0b = (const float*)d_in[8];
    const float* wih1f = (const float*)d_in[9];  const float* whh1f = (const float*)d_in[10];
    const float* bih1f = (const float*)d_in[11]; const float* bhh1f = (const float*)d_in[12];
    const float* wih1b = (const float*)d_in[13]; const float* whh1b = (const float*)d_in[14];
    const float* bih1b = (const float*)d_in[15]; const float* bhh1b = (const float*)d_in[16];
    const float* wproj = (const float*)d_in[17]; const float* bproj = (const float*)d_in[18];
    const float* start_t = (const float*)d_in[19];
    const float* end_t   = (const float*)d_in[20];
    const float* trans_t = (const float*)d_in[21];
    const int* x    = (const int*)d_in[22];
    const int* tags = (const int*)d_in[23];
    const int* mask = (const int*)d_in[24];

    float* ws   = (float*)d_ws;
    float* e_buf = ws;                                  // 16384*300      (reused as h1)
    float* xg    = e_buf + (size_t)Mtok * Ee;           // 2*16384*512
    float* h0    = xg + (size_t)2 * Mtok * 512;         // 16384*256
    float* em    = h0 + (size_t)Mtok * 256;             // 16384*9
    float* num   = em + (size_t)Mtok * Tt;              // 32
    float* h1    = e_buf;                               // alias: e dead after xg layer0
    float* outp  = (float*)d_out;

    embed_gather<<<(Mtok * 75 + 255) / 256, 256, 0, stream>>>(emb, x, e_buf);
    xg_gemm<Ee><<<dim3(8, 128, 2), 256, 0, stream>>>(e_buf, wih0f, wih0b,
                                                     bih0f, bhh0f, bih0b, bhh0b, xg);
    lstm_scan<<<64, 512, 0, stream>>>(xg, whh0f, whh0b, h0);
    xg_gemm<HIDc><<<dim3(8, 128, 2), 256, 0, stream>>>(h0, wih1f, wih1b,
                                                       bih1f, bhh1f, bih1b, bhh1b, xg);
    lstm_scan<<<64, 512, 0, stream>>>(xg, whh1f, whh1b, h1);
    emis_kernel<<<(Mtok * Tt + 255) / 256, 256, 0, stream>>>(h1, wproj, bproj, em);
    crf_num<<<32, 256, 0, stream>>>(em, tags, mask, start_t, end_t, trans_t, num);
    crf_alpha<<<1, 512, 0, stream>>>(em, mask, start_t, end_t, trans_t, num, outp);
}